// Round 4
// baseline (1829.572 us; speedup 1.0000x reference)
//
#include <hip/hip_runtime.h>
#include <math.h>

#define OPI 64
#define RPI 1024
#define N_OBJ 512       // B*OPI
#define R_REL 8192      // B*RPI
#define OBJ_DIM 4096
#define H 512
#define NOC 151
#define NRC 51
#define T_ITERS 3
#define IOU_THRESH 0.3f

typedef unsigned short u16;
typedef unsigned int u32;
typedef __attribute__((ext_vector_type(4))) float f32x4;
typedef __attribute__((ext_vector_type(8))) short bf16x8;
typedef __attribute__((ext_vector_type(4))) short s16x4;
typedef __attribute__((ext_vector_type(8))) short s16x8;

enum { EPI_STORE = 0, EPI_BIAS = 1, EPI_GATE = 3, EPI_NEWH = 4 };

__device__ inline u16 f2bf(float x) {
  u32 u = __float_as_uint(x);
  u32 r = (u + 0x7fffu + ((u >> 16) & 1u)) >> 16;
  return (u16)r;
}
__device__ inline float bf2f(u16 h) { return __uint_as_float(((u32)h) << 16); }

// ---------------------------------------------------------------------------
// Weight prep, coalesced via 64x64 LDS transpose tile.
// ---------------------------------------------------------------------------
__global__ __launch_bounds__(256) void prep_bt(
    const float* __restrict__ W1, int ld1, int K1,
    const float* __restrict__ W2, int ld2, int K2,
    int coloff, int ncols, int N, int Kpad,
    u16* __restrict__ outh, u16* __restrict__ outl)
{
  __shared__ float tile[64][65];
  const int k0 = blockIdx.x * 64;
  const int n0 = blockIdx.y * 64;
  const int t = threadIdx.x;
  const int lane = t & 63;
  const int w = t >> 6;
#pragma unroll
  for (int p = 0; p < 16; ++p) {
    int kl = w * 16 + p;
    int k = k0 + kl;
    int n = n0 + lane;
    float v = 0.f;
    if (n < ncols) {
      if (k < K1) v = W1[(size_t)k * ld1 + coloff + n];
      else if (k - K1 < K2) v = W2[(size_t)(k - K1) * ld2 + coloff + n];
    }
    tile[kl][lane] = v;
  }
  __syncthreads();
#pragma unroll
  for (int p = 0; p < 16; ++p) {
    int nl = w * 16 + p;
    int n = n0 + nl;
    int k = k0 + lane;
    if (n < N && k < Kpad) {
      float v = tile[lane][nl];
      u16 h = f2bf(v);
      outh[(size_t)n * Kpad + k] = h;
      outl[(size_t)n * Kpad + k] = f2bf(v - bf2f(h));
    }
  }
}

// ---------------------------------------------------------------------------
// Split-bf16 MFMA GEMM with register-prefetch pipeline + XCD-aware swizzle.
// C ~= Ah@Bh + Ah@Bl + Al@Bh (fp32 acc). Tile 128x128, 4 waves, 16x16x32 bf16.
// PAIR:  blockIdx.z==1 runs a second independent GEMM (A2/Bt*2/C2, no gather).
// SPLIT: blockIdx.z = K-chunk; raw partials to part[z][M][Npad]; EPI in reduce.
// ---------------------------------------------------------------------------
template<int EPI, bool DUAL, bool GATHER, bool PAIR, bool SPLIT>
__global__ __launch_bounds__(256) void mgemm_k(
    int M, int N, int K1, int K2, int nkt,
    const float* __restrict__ A1, int lda1,
    const float* __restrict__ A2, int lda2,
    const u16* __restrict__ Bth, const u16* __restrict__ Btl,
    const u16* __restrict__ Bth2, const u16* __restrict__ Btl2,
    const float* __restrict__ bias,
    float* __restrict__ C, int ldc, float* __restrict__ C2,
    const int* __restrict__ ridx,
    const float* __restrict__ Hb, int ldh,
    const float* __restrict__ Zin,
    float* __restrict__ Zout, float* __restrict__ RHout,
    float* __restrict__ part, int ktchunk)
{
  __shared__ u16 lAh[128 * 32];
  __shared__ u16 lAl[128 * 32];
  __shared__ u16 lBh[128 * 32];
  __shared__ u16 lBl[128 * 32];
  const int t = threadIdx.x;
  const int lane = t & 63;
  const int wid = t >> 6;
  const int wm = wid >> 1, wn = wid & 1;

  // ---- bijective XCD-aware block swizzle (all grids have nbx*nby % 8 == 0)
  const int nbx = gridDim.x, nby = gridDim.y;
  const int nwg = nbx * nby;
  int orig = blockIdx.y * nbx + blockIdx.x;
  int lid = (orig & 7) * (nwg >> 3) + (orig >> 3);
  const int bx = lid % nbx;
  const int by = lid / nbx;

  const int m0 = by * 128;
  const int n0 = bx * 128;
  const int Kpad = nkt * 32;

  const float* A1p = A1; int ldap = lda1;
  const u16* Bhp = Bth; const u16* Blp = Btl;
  float* Cp = C;
  bool gath = GATHER;
  if (PAIR && blockIdx.z == 1) {
    A1p = A2; ldap = lda2; Bhp = Bth2; Blp = Btl2; Cp = C2; gath = false;
  }

  f32x4 acc[4][4];
#pragma unroll
  for (int m = 0; m < 4; ++m)
#pragma unroll
    for (int n = 0; n < 4; ++n) acc[m][n] = f32x4{0.f, 0.f, 0.f, 0.f};

  const int a_row = t >> 3;
  const int a_kq  = t & 7;
  int g_si[4], g_oi[4];
  if (gath) {
#pragma unroll
    for (int i = 0; i < 4; ++i) {
      int gm = m0 + a_row + i * 32;
      g_si[i] = ridx[gm * 3 + 1];
      g_oi[i] = ridx[gm * 3 + 2];
    }
  }
  const int b_row  = t >> 2;
  const int b_slot = t & 3;

  int ktb = 0, kte = nkt;
  if (SPLIT) {
    ktb = blockIdx.z * ktchunk;
    kte = min(nkt, ktb + ktchunk);
  }

  // prefetch registers
  float4 rA[4], rA2[4];
  s16x8 rBh[2], rBl[2];

  auto loadA = [&](int kt) {
    const int gk = kt * 32 + a_kq * 4;
#pragma unroll
    for (int i = 0; i < 4; ++i) {
      const int gm = m0 + a_row + i * 32;
      if (gath) {
        rA[i]  = *(const float4*)&A1p[(size_t)g_si[i] * ldap + gk];
        rA2[i] = *(const float4*)&A1p[(size_t)g_oi[i] * ldap + gk];
      } else if (!DUAL) {
        rA[i] = *(const float4*)&A1p[(size_t)gm * ldap + gk];
      } else {
        if (gk + 3 < K1) {
          rA[i] = *(const float4*)&A1p[(size_t)gm * lda1 + gk];
        } else if (gk >= K1 && gk + 3 < K1 + K2 && (lda2 & 3) == 0) {
          rA[i] = *(const float4*)&A2[(size_t)gm * lda2 + (gk - K1)];
        } else {
          float xs[4];
#pragma unroll
          for (int e = 0; e < 4; ++e) {
            int gke = gk + e;
            float xv = 0.f;
            if (gke < K1) xv = A1p[(size_t)gm * lda1 + gke];
            else if (gke < K1 + K2) xv = A2[(size_t)gm * lda2 + (gke - K1)];
            xs[e] = xv;
          }
          rA[i] = make_float4(xs[0], xs[1], xs[2], xs[3]);
        }
      }
    }
  };
  auto loadB = [&](int kt) {
    const int k0 = kt * 32;
#pragma unroll
    for (int i = 0; i < 2; ++i) {
      const size_t goff = (size_t)(n0 + b_row + i * 64) * Kpad + k0 + b_slot * 8;
      rBh[i] = *(const s16x8*)&Bhp[goff];
      rBl[i] = *(const s16x8*)&Blp[goff];
    }
  };
  auto stage = [&]() {
#pragma unroll
    for (int i = 0; i < 4; ++i) {
      const int row = a_row + i * 32;
      float x0 = rA[i].x, x1 = rA[i].y, x2 = rA[i].z, x3 = rA[i].w;
      if (gath) { x0 += rA2[i].x; x1 += rA2[i].y; x2 += rA2[i].z; x3 += rA2[i].w; }
      u16 h0 = f2bf(x0), h1 = f2bf(x1), h2 = f2bf(x2), h3 = f2bf(x3);
      s16x4 vh = { (short)h0, (short)h1, (short)h2, (short)h3 };
      s16x4 vl = { (short)f2bf(x0 - bf2f(h0)), (short)f2bf(x1 - bf2f(h1)),
                   (short)f2bf(x2 - bf2f(h2)), (short)f2bf(x3 - bf2f(h3)) };
      const int base = row * 32 + (((a_kq >> 1) ^ ((row >> 1) & 3)) << 3) + (a_kq & 1) * 4;
      *reinterpret_cast<s16x4*>(&lAh[base]) = vh;
      *reinterpret_cast<s16x4*>(&lAl[base]) = vl;
    }
#pragma unroll
    for (int i = 0; i < 2; ++i) {
      const int row = b_row + i * 64;
      const int base = row * 32 + ((b_slot ^ ((row >> 1) & 3)) << 3);
      *reinterpret_cast<s16x8*>(&lBh[base]) = rBh[i];
      *reinterpret_cast<s16x8*>(&lBl[base]) = rBl[i];
    }
  };

  loadA(ktb);
  loadB(ktb);

  for (int kt = ktb; kt < kte; ++kt) {
    stage();
    __syncthreads();
    if (kt + 1 < kte) { loadA(kt + 1); loadB(kt + 1); }   // in flight under MFMAs
    // ---- fragments + MFMA
    const int fr = lane & 15;
    const int kg = lane >> 4;
    bf16x8 ah[4], al[4], bh[4], bl[4];
#pragma unroll
    for (int m = 0; m < 4; ++m) {
      const int r = wm * 64 + m * 16 + fr;
      const int addr = r * 32 + ((kg ^ ((r >> 1) & 3)) << 3);
      ah[m] = *reinterpret_cast<const bf16x8*>(&lAh[addr]);
      al[m] = *reinterpret_cast<const bf16x8*>(&lAl[addr]);
    }
#pragma unroll
    for (int n = 0; n < 4; ++n) {
      const int r = wn * 64 + n * 16 + fr;
      const int addr = r * 32 + ((kg ^ ((r >> 1) & 3)) << 3);
      bh[n] = *reinterpret_cast<const bf16x8*>(&lBh[addr]);
      bl[n] = *reinterpret_cast<const bf16x8*>(&lBl[addr]);
    }
#pragma unroll
    for (int m = 0; m < 4; ++m)
#pragma unroll
      for (int n = 0; n < 4; ++n) {
        acc[m][n] = __builtin_amdgcn_mfma_f32_16x16x32_bf16(ah[m], bh[n], acc[m][n], 0, 0, 0);
        acc[m][n] = __builtin_amdgcn_mfma_f32_16x16x32_bf16(ah[m], bl[n], acc[m][n], 0, 0, 0);
        acc[m][n] = __builtin_amdgcn_mfma_f32_16x16x32_bf16(al[m], bh[n], acc[m][n], 0, 0, 0);
      }
    __syncthreads();
  }

  // ---- epilogue (C/D layout: col = lane&15, row = (lane>>4)*4 + j)
  const int col = lane & 15;
  const int rb = (lane >> 4) * 4;
  if (SPLIT) {
    const int Npad = gridDim.x * 128;
    float* pp = part + (size_t)blockIdx.z * M * Npad;
#pragma unroll
    for (int m = 0; m < 4; ++m)
#pragma unroll
      for (int n = 0; n < 4; ++n) {
        const int gn = n0 + wn * 64 + n * 16 + col;
#pragma unroll
        for (int j = 0; j < 4; ++j) {
          const int gm = m0 + wm * 64 + m * 16 + rb + j;
          pp[(size_t)gm * Npad + gn] = acc[m][n][j];
        }
      }
    return;
  }
#pragma unroll
  for (int m = 0; m < 4; ++m) {
#pragma unroll
    for (int n = 0; n < 4; ++n) {
      const int gn = n0 + wn * 64 + n * 16 + col;
      if (gn >= N) continue;
#pragma unroll
      for (int j = 0; j < 4; ++j) {
        const int gm = m0 + wm * 64 + m * 16 + rb + j;
        float v = acc[m][n][j];
        if (EPI == EPI_STORE) {
          Cp[(size_t)gm * ldc + gn] = v;
        } else if (EPI == EPI_BIAS) {
          Cp[(size_t)gm * ldc + gn] = v + bias[gn];
        } else if (EPI == EPI_GATE) {
          float g = 1.f / (1.f + expf(-(v + bias[gn])));
          int half = N >> 1;
          if (gn < half) Zout[(size_t)gm * half + gn] = g;
          else RHout[(size_t)gm * half + (gn - half)] = g * Hb[(size_t)gm * ldh + (gn - half)];
        } else if (EPI == EPI_NEWH) {
          float nv = tanhf(v + bias[gn]);
          float z = Zin[(size_t)gm * N + gn];
          float h = Hb[(size_t)gm * ldh + gn];
          Cp[(size_t)gm * ldc + gn] = (1.f - z) * h + z * nv;
        }
      }
    }
  }
}

// ---------------------------------------------------------------------------
// Split-K reduce + epilogue.
// ---------------------------------------------------------------------------
template<int EPI>
__global__ __launch_bounds__(256) void epi_reduce(
    int S, int M, int N, int Npad,
    const float* __restrict__ part, const float* __restrict__ bias,
    float* __restrict__ C, int ldc,
    const float* __restrict__ Hb, int ldh,
    const float* __restrict__ Zin,
    float* __restrict__ Zout, float* __restrict__ RHout)
{
  int idx = blockIdx.x * 256 + threadIdx.x;
  if (idx >= M * Npad) return;
  int m = idx / Npad;
  int n = idx - m * Npad;
  if (n >= N) return;
  size_t stride = (size_t)M * Npad;
  float v = 0.f;
  for (int s = 0; s < S; ++s) v += part[s * stride + idx];
  if (EPI == EPI_BIAS) {
    C[(size_t)m * ldc + n] = v + bias[n];
  } else if (EPI == EPI_GATE) {
    float g = 1.f / (1.f + expf(-(v + bias[n])));
    int half = N >> 1;
    if (n < half) Zout[(size_t)m * half + n] = g;
    else RHout[(size_t)m * half + (n - half)] = g * Hb[(size_t)m * ldh + (n - half)];
  } else if (EPI == EPI_NEWH) {
    float nv = tanhf(v + bias[n]);
    float z = Zin[(size_t)m * N + n];
    float h = Hb[(size_t)m * ldh + n];
    C[(size_t)m * ldc + n] = (1.f - z) * h + z * nv;
  }
}

// row softmax over NOC=151 columns, one block per row
__global__ __launch_bounds__(256) void softmax_k(const float* __restrict__ X,
                                                 float* __restrict__ P)
{
  int row = blockIdx.x;
  int t = threadIdx.x;
  __shared__ float red[4];
  float x = (t < NOC) ? X[row * NOC + t] : -3.4e38f;
  float m = x;
#pragma unroll
  for (int o = 32; o > 0; o >>= 1) m = fmaxf(m, __shfl_xor(m, o, 64));
  if ((t & 63) == 0) red[t >> 6] = m;
  __syncthreads();
  float mm = fmaxf(fmaxf(red[0], red[1]), fmaxf(red[2], red[3]));
  float e = (t < NOC) ? expf(x - mm) : 0.f;
  float s = e;
#pragma unroll
  for (int o = 32; o > 0; o >>= 1) s += __shfl_xor(s, o, 64);
  __syncthreads();
  if ((t & 63) == 0) red[t >> 6] = s;
  __syncthreads();
  float ss = red[0] + red[1] + red[2] + red[3];
  if (t < NOC) P[row * NOC + t] = e / ss;
}

// deterministic scatter-free m_obj
__global__ __launch_bounds__(256) void m_obj_gather_k(const float* __restrict__ hm,
                                                      const int* __restrict__ ridx,
                                                      float* __restrict__ m_obj)
{
  int n = blockIdx.x;
  int im = n >> 6;
  int col = threadIdx.x;
  float acc0 = 0.f, acc1 = 0.f;
  int r0 = im * RPI, r1 = r0 + RPI;
  for (int r = r0; r < r1; ++r) {
    int s = ridx[r * 3 + 1];
    int o = ridx[r * 3 + 2];
    int cnt = (s == n) + (o == n);
    if (cnt) {
      float f = (float)cnt;
      acc0 = fmaf(f, hm[r * H + col], acc0);
      acc1 = fmaf(f, hm[r * H + col + 256], acc1);
    }
  }
  m_obj[n * H + col] = acc0;
  m_obj[n * H + col + 256] = acc1;
}

// per-class NMS (stable descending bitonic sort + greedy suppression)
__global__ __launch_bounds__(512) void nms_k(const float* __restrict__ probs2,
                                             const float* __restrict__ boxes,
                                             float* __restrict__ keepmask)
{
  int c = blockIdx.x + 1;
  int t = threadIdx.x;
  __shared__ float sc[512];
  __shared__ int   si[512];
  __shared__ float bx0[512], by0[512], bx1[512], by1[512], sar[512];
  __shared__ int   skeep[512];

  sc[t] = probs2[t * NOC + c];
  si[t] = t;
  __syncthreads();

  for (int k = 2; k <= 512; k <<= 1) {
    for (int j = k >> 1; j > 0; j >>= 1) {
      int p = t ^ j;
      if (p > t) {
        float s1 = sc[t], s2 = sc[p];
        int   i1 = si[t], i2 = si[p];
        bool tBefore = (s1 > s2) || (s1 == s2 && i1 < i2);
        bool up = ((t & k) == 0);
        if (up != tBefore) { sc[t] = s2; sc[p] = s1; si[t] = i2; si[p] = i1; }
      }
      __syncthreads();
    }
  }

  {
    const float* b = &boxes[(si[t] * NOC + c) * 4];
    float x0 = b[0], y0 = b[1], x1 = b[2], y1 = b[3];
    bx0[t] = x0; by0[t] = y0; bx1[t] = x1; by1[t] = y1;
    sar[t] = (x1 - x0) * (y1 - y0);
    skeep[t] = 1;
  }
  __syncthreads();

  for (int i = 0; i < 511; ++i) {
    if (skeep[i] && t > i && skeep[t]) {
      float lx = fmaxf(bx0[i], bx0[t]);
      float ly = fmaxf(by0[i], by0[t]);
      float rx = fminf(bx1[i], bx1[t]);
      float ry = fminf(by1[i], by1[t]);
      float w = fmaxf(rx - lx, 0.f);
      float h = fmaxf(ry - ly, 0.f);
      float inter = w * h;
      float iou = inter / (sar[i] + sar[t] - inter + 1e-9f);
      if (iou > IOU_THRESH) skeep[t] = 0;
    }
    __syncthreads();
  }

  keepmask[(c - 1) * N_OBJ + si[t]] = skeep[t] ? 1.f : 0.f;
}

__global__ void pred_k(const float* __restrict__ probs2,
                       const float* __restrict__ keepmask,
                       float* __restrict__ out)
{
  int i = threadIdx.x + blockIdx.x * 256;
  if (i >= N_OBJ) return;
  float best = -1.f;
  int bc = 0;
  for (int c = 0; c < NOC - 1; ++c) {
    float v = keepmask[c * N_OBJ + i] * probs2[i * NOC + c + 1];
    if (v > best) { best = v; bc = c; }
  }
  out[i] = (float)(bc + 1);
}

extern "C" void kernel_launch(void* const* d_in, const int* in_sizes, int n_in,
                              void* d_out, int out_size, void* d_ws, size_t ws_size,
                              hipStream_t stream) {
  const float* obj_fmaps  = (const float*)d_in[1];
  const float* obj_logits = (const float*)d_in[2];
  const int*   rel_inds   = (const int*)d_in[3];
  const float* vr         = (const float*)d_in[4];
  const float* boxes      = (const float*)d_in[5];
  const float* W_obj_proj = (const float*)d_in[6];
  const float* b_obj_proj = (const float*)d_in[7];
  const float* W_rel_proj = (const float*)d_in[8];
  const float* b_rel_proj = (const float*)d_in[9];
  const float* W_emb      = (const float*)d_in[10];
  const float* W_msg_rel  = (const float*)d_in[11];
  const float* W_msg_obj  = (const float*)d_in[12];
  const float* W_gru_obj  = (const float*)d_in[13];
  const float* U_gru_obj  = (const float*)d_in[14];
  const float* b_gru_obj  = (const float*)d_in[15];
  const float* W_gru_rel  = (const float*)d_in[16];
  const float* U_gru_rel  = (const float*)d_in[17];
  const float* b_gru_rel  = (const float*)d_in[18];
  const float* W_cls_rel  = (const float*)d_in[19];
  const float* b_cls_rel  = (const float*)d_in[20];
  const float* W_cls_obj  = (const float*)d_in[21];
  const float* b_cls_obj  = (const float*)d_in[22];

  float* ws = (float*)d_ws;
  const size_t RH = (size_t)R_REL * H;
  const size_t NH = (size_t)N_OBJ * H;
  float* h_rel  = ws;
  float* m_rel  = h_rel  + RH;   // also aliased as split-K partial scratch
  float* z_rel  = m_rel  + RH;   // aliased with hm
  float* rh_rel = z_rel  + RH;
  float* h_obj  = rh_rel + RH;
  float* m_obj  = h_obj  + NH;
  float* z_obj  = m_obj  + NH;
  float* rh_obj = z_obj  + NH;
  float* obj_probs  = rh_obj + NH;
  float* obj_probs2 = obj_probs  + (size_t)N_OBJ * NOC;
  float* keepmask   = obj_probs2 + (size_t)N_OBJ * NOC;
  float* hm   = z_rel;
  float* part = m_rel;
  float* fend = keepmask + (size_t)(NOC - 1) * N_OBJ;

  u16* bt = (u16*)fend;
  const int KP_HOBJ = 4256;
  const int KP_HREL = 4096;
  const int KP_MSG  = 512;
  const int KP_GRU  = 1024;
  const int KP_CLS  = 512;
  u16* p = bt;
  u16* bt_hobj_h = p; p += (size_t)H * KP_HOBJ;      u16* bt_hobj_l = p; p += (size_t)H * KP_HOBJ;
  u16* bt_hrel_h = p; p += (size_t)H * KP_HREL;      u16* bt_hrel_l = p; p += (size_t)H * KP_HREL;
  u16* bt_mrel_h = p; p += (size_t)H * KP_MSG;       u16* bt_mrel_l = p; p += (size_t)H * KP_MSG;
  u16* bt_hm_h   = p; p += (size_t)H * KP_MSG;       u16* bt_hm_l   = p; p += (size_t)H * KP_MSG;
  u16* bt_gr_h   = p; p += (size_t)2 * H * KP_GRU;   u16* bt_gr_l   = p; p += (size_t)2 * H * KP_GRU;
  u16* bt_nr_h   = p; p += (size_t)H * KP_GRU;       u16* bt_nr_l   = p; p += (size_t)H * KP_GRU;
  u16* bt_go_h   = p; p += (size_t)2 * H * KP_GRU;   u16* bt_go_l   = p; p += (size_t)2 * H * KP_GRU;
  u16* bt_no_h   = p; p += (size_t)H * KP_GRU;       u16* bt_no_l   = p; p += (size_t)H * KP_GRU;
  u16* bt_cr_h   = p; p += (size_t)128 * KP_CLS;     u16* bt_cr_l   = p; p += (size_t)128 * KP_CLS;
  u16* bt_co_h   = p; p += (size_t)256 * KP_CLS;     u16* bt_co_l   = p; p += (size_t)256 * KP_CLS;

  float* out_logits = (float*)d_out;
  float* out_preds  = out_logits + (size_t)N_OBJ * NOC;
  float* out_rel    = out_preds + N_OBJ;

  dim3 blk(256);
#define PREP(W1, ld1, K1, W2, ld2, K2, coff, NC, NN, KP, oh, ol) \
  prep_bt<<<dim3(((KP) + 63) / 64, ((NN) + 63) / 64), 256, 0, stream>>>( \
      W1, ld1, K1, W2, ld2, K2, coff, NC, NN, KP, oh, ol)

  PREP(W_obj_proj, H, OBJ_DIM, W_emb, H, NOC, 0, H, H, KP_HOBJ, bt_hobj_h, bt_hobj_l);
  PREP(W_rel_proj, H, OBJ_DIM, (const float*)nullptr, 0, 0, 0, H, H, KP_HREL, bt_hrel_h, bt_hrel_l);
  PREP(W_msg_rel, H, H, (const float*)nullptr, 0, 0, 0, H, H, KP_MSG, bt_mrel_h, bt_mrel_l);
  PREP(W_msg_obj, H, H, (const float*)nullptr, 0, 0, 0, H, H, KP_MSG, bt_hm_h, bt_hm_l);
  PREP(W_gru_rel, 3 * H, H, U_gru_rel, 3 * H, H, 0, 2 * H, 2 * H, KP_GRU, bt_gr_h, bt_gr_l);
  PREP(W_gru_rel, 3 * H, H, U_gru_rel, 3 * H, H, 2 * H, H, H, KP_GRU, bt_nr_h, bt_nr_l);
  PREP(W_gru_obj, 3 * H, H, U_gru_obj, 3 * H, H, 0, 2 * H, 2 * H, KP_GRU, bt_go_h, bt_go_l);
  PREP(W_gru_obj, 3 * H, H, U_gru_obj, 3 * H, H, 2 * H, H, H, KP_GRU, bt_no_h, bt_no_l);
  PREP(W_cls_rel, NRC, H, (const float*)nullptr, 0, 0, 0, NRC, 128, KP_CLS, bt_cr_h, bt_cr_l);
  PREP(W_cls_obj, NOC, H, (const float*)nullptr, 0, 0, 0, NOC, 256, KP_CLS, bt_co_h, bt_co_l);

  softmax_k<<<N_OBJ, 256, 0, stream>>>(obj_logits, obj_probs);

#define MG(EPI, DUAL, GATH, PAIR, SPLIT, grid, M, N, K1, K2, nkt, A1, lda1, A2, lda2, \
           Bh, Bl, Bh2, Bl2, bias, C, ldc, C2, ridx, Hb, ldh, Zin, Zo, RHo, part, ktc) \
  mgemm_k<EPI, DUAL, GATH, PAIR, SPLIT><<<grid, blk, 0, stream>>>( \
      M, N, K1, K2, nkt, A1, lda1, A2, lda2, Bh, Bl, Bh2, Bl2, bias, C, ldc, C2, \
      ridx, Hb, ldh, Zin, Zo, RHo, part, ktc)

  // h_obj = obj_fmaps @ W_obj_proj + obj_probs @ W_emb + b  (split-K S=8)
  MG(EPI_STORE, true, false, false, true, dim3(4, 4, 8), N_OBJ, H, OBJ_DIM, NOC, KP_HOBJ / 32,
     obj_fmaps, OBJ_DIM, obj_probs, NOC, bt_hobj_h, bt_hobj_l, nullptr, nullptr,
     nullptr, nullptr, 0, nullptr, nullptr, nullptr, 0, nullptr, nullptr, nullptr, part, 17);
  epi_reduce<EPI_BIAS><<<(N_OBJ * H + 255) / 256, blk, 0, stream>>>(
      8, N_OBJ, H, H, part, b_obj_proj, h_obj, H, nullptr, 0, nullptr, nullptr, nullptr);

  // h_rel = vr @ W_rel_proj + b_rel_proj
  MG(EPI_BIAS, false, false, false, false, dim3(4, 64), R_REL, H, OBJ_DIM, 0, KP_HREL / 32,
     vr, OBJ_DIM, nullptr, 0, bt_hrel_h, bt_hrel_l, nullptr, nullptr,
     b_rel_proj, h_rel, H, nullptr, nullptr, nullptr, 0, nullptr, nullptr, nullptr, nullptr, 0);

  for (int it = 0; it < T_ITERS; ++it) {
    // paired: z=0: m_rel = (h_obj[s]+h_obj[o]) @ W_msg_rel ; z=1: hm = h_rel @ W_msg_obj
    MG(EPI_STORE, false, true, true, false, dim3(4, 64, 2), R_REL, H, H, 0, KP_MSG / 32,
       h_obj, H, h_rel, H, bt_mrel_h, bt_mrel_l, bt_hm_h, bt_hm_l,
       nullptr, m_rel, H, hm, rel_inds, nullptr, 0, nullptr, nullptr, nullptr, nullptr, 0);
    m_obj_gather_k<<<N_OBJ, 256, 0, stream>>>(hm, rel_inds, m_obj);

    // GRU rel gates
    MG(EPI_GATE, true, false, false, false, dim3(8, 64), R_REL, 2 * H, H, H, KP_GRU / 32,
       m_rel, H, h_rel, H, bt_gr_h, bt_gr_l, nullptr, nullptr,
       b_gru_rel, nullptr, 0, nullptr, nullptr, h_rel, H, nullptr, z_rel, rh_rel, nullptr, 0);
    // GRU rel candidate + h update
    MG(EPI_NEWH, true, false, false, false, dim3(4, 64), R_REL, H, H, H, KP_GRU / 32,
       m_rel, H, rh_rel, H, bt_nr_h, bt_nr_l, nullptr, nullptr,
       b_gru_rel + 2 * H, h_rel, H, nullptr, nullptr, h_rel, H, z_rel, nullptr, nullptr, nullptr, 0);

    // GRU obj gates (split-K S=8)
    MG(EPI_STORE, true, false, false, true, dim3(8, 4, 8), N_OBJ, 2 * H, H, H, KP_GRU / 32,
       m_obj, H, h_obj, H, bt_go_h, bt_go_l, nullptr, nullptr,
       nullptr, nullptr, 0, nullptr, nullptr, nullptr, 0, nullptr, nullptr, nullptr, part, 4);
    epi_reduce<EPI_GATE><<<(N_OBJ * 2 * H + 255) / 256, blk, 0, stream>>>(
        8, N_OBJ, 2 * H, 2 * H, part, b_gru_obj, nullptr, 0, h_obj, H, nullptr, z_obj, rh_obj);
    // GRU obj candidate + h update (split-K S=8)
    MG(EPI_STORE, true, false, false, true, dim3(4, 4, 8), N_OBJ, H, H, H, KP_GRU / 32,
       m_obj, H, rh_obj, H, bt_no_h, bt_no_l, nullptr, nullptr,
       nullptr, nullptr, 0, nullptr, nullptr, nullptr, 0, nullptr, nullptr, nullptr, part, 4);
    epi_reduce<EPI_NEWH><<<(N_OBJ * H + 255) / 256, blk, 0, stream>>>(
        8, N_OBJ, H, H, part, b_gru_obj + 2 * H, h_obj, H, h_obj, H, z_obj, nullptr, nullptr);
  }

  // rel_logits = h_rel @ W_cls_rel + b (N=51, padded bt to 128)
  MG(EPI_BIAS, false, false, false, false, dim3(1, 64), R_REL, NRC, H, 0, KP_CLS / 32,
     h_rel, H, nullptr, 0, bt_cr_h, bt_cr_l, nullptr, nullptr,
     b_cls_rel, out_rel, NRC, nullptr, nullptr, nullptr, 0, nullptr, nullptr, nullptr, nullptr, 0);
  // obj_logits_out = h_obj @ W_cls_obj + b (N=151, padded bt to 256, split-K S=4)
  MG(EPI_STORE, false, false, false, true, dim3(2, 4, 4), N_OBJ, NOC, H, 0, KP_CLS / 32,
     h_obj, H, nullptr, 0, bt_co_h, bt_co_l, nullptr, nullptr,
     nullptr, nullptr, 0, nullptr, nullptr, nullptr, 0, nullptr, nullptr, nullptr, part, 4);
  epi_reduce<EPI_BIAS><<<(N_OBJ * 256 + 255) / 256, blk, 0, stream>>>(
      4, N_OBJ, NOC, 256, part, b_cls_obj, out_logits, NOC, nullptr, 0, nullptr, nullptr, nullptr);

  // softmax -> NMS -> preds
  softmax_k<<<N_OBJ, 256, 0, stream>>>(out_logits, obj_probs2);
  nms_k<<<NOC - 1, 512, 0, stream>>>(obj_probs2, boxes, keepmask);
  pred_k<<<2, 256, 0, stream>>>(obj_probs2, keepmask, out_preds);
}

// Round 5
// 1497.461 us; speedup vs baseline: 1.2218x; 1.2218x over previous
//
#include <hip/hip_runtime.h>
#include <math.h>

#define OPI 64
#define RPI 1024
#define N_OBJ 512       // B*OPI
#define R_REL 8192      // B*RPI
#define OBJ_DIM 4096
#define H 512
#define NOC 151
#define NRC 51
#define T_ITERS 3
#define IOU_THRESH 0.3f

typedef unsigned short u16;
typedef unsigned int u32;
typedef __attribute__((ext_vector_type(4))) float f32x4;
typedef __attribute__((ext_vector_type(8))) short bf16x8;
typedef __attribute__((ext_vector_type(4))) short s16x4;
typedef __attribute__((ext_vector_type(8))) short s16x8;

enum { EPI_STORE = 0, EPI_BIAS = 1, EPI_GATE = 3, EPI_NEWH = 4 };

__device__ inline u16 f2bf(float x) {
  u32 u = __float_as_uint(x);
  u32 r = (u + 0x7fffu + ((u >> 16) & 1u)) >> 16;
  return (u16)r;
}
__device__ inline float bf2f(u16 h) { return __uint_as_float(((u32)h) << 16); }

// ---------------------------------------------------------------------------
// Weight prep, coalesced via 64x64 LDS transpose tile.
// ---------------------------------------------------------------------------
__global__ __launch_bounds__(256) void prep_bt(
    const float* __restrict__ W1, int ld1, int K1,
    const float* __restrict__ W2, int ld2, int K2,
    int coloff, int ncols, int N, int Kpad,
    u16* __restrict__ outh, u16* __restrict__ outl)
{
  __shared__ float tile[64][65];
  const int k0 = blockIdx.x * 64;
  const int n0 = blockIdx.y * 64;
  const int t = threadIdx.x;
  const int lane = t & 63;
  const int w = t >> 6;
#pragma unroll
  for (int p = 0; p < 16; ++p) {
    int kl = w * 16 + p;
    int k = k0 + kl;
    int n = n0 + lane;
    float v = 0.f;
    if (n < ncols) {
      if (k < K1) v = W1[(size_t)k * ld1 + coloff + n];
      else if (k - K1 < K2) v = W2[(size_t)(k - K1) * ld2 + coloff + n];
    }
    tile[kl][lane] = v;
  }
  __syncthreads();
#pragma unroll
  for (int p = 0; p < 16; ++p) {
    int nl = w * 16 + p;
    int n = n0 + nl;
    int k = k0 + lane;
    if (n < N && k < Kpad) {
      float v = tile[lane][nl];
      u16 h = f2bf(v);
      outh[(size_t)n * Kpad + k] = h;
      outl[(size_t)n * Kpad + k] = f2bf(v - bf2f(h));
    }
  }
}

// ---------------------------------------------------------------------------
// Split-bf16 MFMA GEMM. 512 threads = 8 waves (2m x 4n), 128x128 tile, BK=32,
// double-buffered LDS (one barrier per K-step), register prefetch,
// XCD-aware bijective block swizzle.
// C ~= Ah@Bh + Ah@Bl + Al@Bh (fp32 acc in AGPRs).
// PAIR:  blockIdx.z==1 runs a second independent GEMM (A2/Bt*2/C2, no gather).
// SPLIT: blockIdx.z = K-chunk; raw partials to part[z][M][Npad]; EPI in reduce.
// ---------------------------------------------------------------------------
template<int EPI, bool DUAL, bool GATHER, bool PAIR, bool SPLIT>
__global__ __launch_bounds__(512, 2) void mgemm_k(
    int M, int N, int K1, int K2, int nkt,
    const float* __restrict__ A1, int lda1,
    const float* __restrict__ A2, int lda2,
    const u16* __restrict__ Bth, const u16* __restrict__ Btl,
    const u16* __restrict__ Bth2, const u16* __restrict__ Btl2,
    const float* __restrict__ bias,
    float* __restrict__ C, int ldc, float* __restrict__ C2,
    const int* __restrict__ ridx,
    const float* __restrict__ Hb, int ldh,
    const float* __restrict__ Zin,
    float* __restrict__ Zout, float* __restrict__ RHout,
    float* __restrict__ part, int ktchunk)
{
  __shared__ u16 lAh[2][128 * 32];
  __shared__ u16 lAl[2][128 * 32];
  __shared__ u16 lBh[2][128 * 32];
  __shared__ u16 lBl[2][128 * 32];
  const int t = threadIdx.x;
  const int lane = t & 63;
  const int wid = t >> 6;          // 0..7
  const int wm = wid >> 2;         // 0..1  (64-row half)
  const int wn = wid & 3;          // 0..3  (32-col quarter)

  // bijective XCD-aware swizzle over (x,y); all grids have nbx*nby % 8 == 0
  const int nbx = gridDim.x, nby = gridDim.y;
  const int nwg = nbx * nby;
  int orig = blockIdx.y * nbx + blockIdx.x;
  int lid = (orig & 7) * (nwg >> 3) + (orig >> 3);
  const int bx = lid % nbx;
  const int by = lid / nbx;

  const int m0 = by * 128;
  const int n0 = bx * 128;
  const int Kpad = nkt * 32;

  const float* A1p = A1; int ldap = lda1;
  const u16* Bhp = Bth; const u16* Blp = Btl;
  float* Cp = C;
  bool gath = GATHER;
  if (PAIR && blockIdx.z == 1) {
    A1p = A2; ldap = lda2; Bhp = Bth2; Blp = Btl2; Cp = C2; gath = false;
  }

  f32x4 acc[4][2];
#pragma unroll
  for (int m = 0; m < 4; ++m)
#pragma unroll
    for (int n = 0; n < 2; ++n) acc[m][n] = f32x4{0.f, 0.f, 0.f, 0.f};

  const int a_row = t >> 3;        // 0..63 (+64 for i=1)
  const int a_kq  = t & 7;
  int g_si[2], g_oi[2];
  if (gath) {
#pragma unroll
    for (int i = 0; i < 2; ++i) {
      int gm = m0 + a_row + i * 64;
      g_si[i] = ridx[gm * 3 + 1];
      g_oi[i] = ridx[gm * 3 + 2];
    }
  }
  const int b_row  = t >> 2;       // 0..127
  const int b_slot = t & 3;

  int ktb = 0, kte = nkt;
  if (SPLIT) {
    ktb = blockIdx.z * ktchunk;
    kte = min(nkt, ktb + ktchunk);
  }

  float4 rA[2], rA2[2];
  s16x8 rBh, rBl;

  auto loadA = [&](int kt) {
    const int gk = kt * 32 + a_kq * 4;
#pragma unroll
    for (int i = 0; i < 2; ++i) {
      const int gm = m0 + a_row + i * 64;
      if (gath) {
        rA[i]  = *(const float4*)&A1p[(size_t)g_si[i] * ldap + gk];
        rA2[i] = *(const float4*)&A1p[(size_t)g_oi[i] * ldap + gk];
      } else if (!DUAL) {
        rA[i] = *(const float4*)&A1p[(size_t)gm * ldap + gk];
      } else {
        if (gk + 3 < K1) {
          rA[i] = *(const float4*)&A1p[(size_t)gm * lda1 + gk];
        } else if (gk >= K1 && gk + 3 < K1 + K2 && (lda2 & 3) == 0) {
          rA[i] = *(const float4*)&A2[(size_t)gm * lda2 + (gk - K1)];
        } else {
          float xs[4];
#pragma unroll
          for (int e = 0; e < 4; ++e) {
            int gke = gk + e;
            float xv = 0.f;
            if (gke < K1) xv = A1p[(size_t)gm * lda1 + gke];
            else if (gke < K1 + K2) xv = A2[(size_t)gm * lda2 + (gke - K1)];
            xs[e] = xv;
          }
          rA[i] = make_float4(xs[0], xs[1], xs[2], xs[3]);
        }
      }
    }
  };
  auto loadB = [&](int kt) {
    const size_t goff = (size_t)(n0 + b_row) * Kpad + kt * 32 + b_slot * 8;
    rBh = *(const s16x8*)&Bhp[goff];
    rBl = *(const s16x8*)&Blp[goff];
  };
  auto stage = [&](int buf) {
#pragma unroll
    for (int i = 0; i < 2; ++i) {
      const int row = a_row + i * 64;
      float x0 = rA[i].x, x1 = rA[i].y, x2 = rA[i].z, x3 = rA[i].w;
      if (gath) { x0 += rA2[i].x; x1 += rA2[i].y; x2 += rA2[i].z; x3 += rA2[i].w; }
      u16 h0 = f2bf(x0), h1 = f2bf(x1), h2 = f2bf(x2), h3 = f2bf(x3);
      s16x4 vh = { (short)h0, (short)h1, (short)h2, (short)h3 };
      s16x4 vl = { (short)f2bf(x0 - bf2f(h0)), (short)f2bf(x1 - bf2f(h1)),
                   (short)f2bf(x2 - bf2f(h2)), (short)f2bf(x3 - bf2f(h3)) };
      const int base = row * 32 + (((a_kq >> 1) ^ ((row >> 1) & 3)) << 3) + (a_kq & 1) * 4;
      *reinterpret_cast<s16x4*>(&lAh[buf][base]) = vh;
      *reinterpret_cast<s16x4*>(&lAl[buf][base]) = vl;
    }
    {
      const int base = b_row * 32 + ((b_slot ^ ((b_row >> 1) & 3)) << 3);
      *reinterpret_cast<s16x8*>(&lBh[buf][base]) = rBh;
      *reinterpret_cast<s16x8*>(&lBl[buf][base]) = rBl;
    }
  };

  const int fr = lane & 15;
  const int kg = lane >> 4;

  if (ktb < kte) {
    loadA(ktb);
    loadB(ktb);
    stage(0);
    __syncthreads();
    const int nk = kte - ktb;
    for (int kk = 0; kk < nk; ++kk) {
      const int cur = kk & 1;
      const bool more = (kk + 1 < nk);
      if (more) { loadA(ktb + kk + 1); loadB(ktb + kk + 1); }
      // ---- fragments + MFMA from buf[cur]
      bf16x8 ah[4], al[4], bh[2], bl[2];
#pragma unroll
      for (int m = 0; m < 4; ++m) {
        const int r = wm * 64 + m * 16 + fr;
        const int addr = r * 32 + ((kg ^ ((r >> 1) & 3)) << 3);
        ah[m] = *reinterpret_cast<const bf16x8*>(&lAh[cur][addr]);
        al[m] = *reinterpret_cast<const bf16x8*>(&lAl[cur][addr]);
      }
#pragma unroll
      for (int n = 0; n < 2; ++n) {
        const int r = wn * 32 + n * 16 + fr;
        const int addr = r * 32 + ((kg ^ ((r >> 1) & 3)) << 3);
        bh[n] = *reinterpret_cast<const bf16x8*>(&lBh[cur][addr]);
        bl[n] = *reinterpret_cast<const bf16x8*>(&lBl[cur][addr]);
      }
#pragma unroll
      for (int m = 0; m < 4; ++m)
#pragma unroll
        for (int n = 0; n < 2; ++n) {
          acc[m][n] = __builtin_amdgcn_mfma_f32_16x16x32_bf16(ah[m], bh[n], acc[m][n], 0, 0, 0);
          acc[m][n] = __builtin_amdgcn_mfma_f32_16x16x32_bf16(ah[m], bl[n], acc[m][n], 0, 0, 0);
          acc[m][n] = __builtin_amdgcn_mfma_f32_16x16x32_bf16(al[m], bh[n], acc[m][n], 0, 0, 0);
        }
      if (more) stage(cur ^ 1);
      __syncthreads();
    }
  }

  // ---- epilogue (C/D layout: col = lane&15, row = (lane>>4)*4 + j)
  const int col = lane & 15;
  const int rb = (lane >> 4) * 4;
  if (SPLIT) {
    const int Npad = gridDim.x * 128;
    float* pp = part + (size_t)blockIdx.z * M * Npad;
#pragma unroll
    for (int m = 0; m < 4; ++m)
#pragma unroll
      for (int n = 0; n < 2; ++n) {
        const int gn = n0 + wn * 32 + n * 16 + col;
#pragma unroll
        for (int j = 0; j < 4; ++j) {
          const int gm = m0 + wm * 64 + m * 16 + rb + j;
          pp[(size_t)gm * Npad + gn] = acc[m][n][j];
        }
      }
    return;
  }
#pragma unroll
  for (int m = 0; m < 4; ++m) {
#pragma unroll
    for (int n = 0; n < 2; ++n) {
      const int gn = n0 + wn * 32 + n * 16 + col;
      if (gn >= N) continue;
#pragma unroll
      for (int j = 0; j < 4; ++j) {
        const int gm = m0 + wm * 64 + m * 16 + rb + j;
        float v = acc[m][n][j];
        if (EPI == EPI_STORE) {
          Cp[(size_t)gm * ldc + gn] = v;
        } else if (EPI == EPI_BIAS) {
          Cp[(size_t)gm * ldc + gn] = v + bias[gn];
        } else if (EPI == EPI_GATE) {
          float g = 1.f / (1.f + expf(-(v + bias[gn])));
          int half = N >> 1;
          if (gn < half) Zout[(size_t)gm * half + gn] = g;
          else RHout[(size_t)gm * half + (gn - half)] = g * Hb[(size_t)gm * ldh + (gn - half)];
        } else if (EPI == EPI_NEWH) {
          float nv = tanhf(v + bias[gn]);
          float z = Zin[(size_t)gm * N + gn];
          float h = Hb[(size_t)gm * ldh + gn];
          Cp[(size_t)gm * ldc + gn] = (1.f - z) * h + z * nv;
        }
      }
    }
  }
}

// ---------------------------------------------------------------------------
// Split-K reduce + epilogue.
// ---------------------------------------------------------------------------
template<int EPI>
__global__ __launch_bounds__(256) void epi_reduce(
    int S, int M, int N, int Npad,
    const float* __restrict__ part, const float* __restrict__ bias,
    float* __restrict__ C, int ldc,
    const float* __restrict__ Hb, int ldh,
    const float* __restrict__ Zin,
    float* __restrict__ Zout, float* __restrict__ RHout)
{
  int idx = blockIdx.x * 256 + threadIdx.x;
  if (idx >= M * Npad) return;
  int m = idx / Npad;
  int n = idx - m * Npad;
  if (n >= N) return;
  size_t stride = (size_t)M * Npad;
  float v = 0.f;
  for (int s = 0; s < S; ++s) v += part[s * stride + idx];
  if (EPI == EPI_BIAS) {
    C[(size_t)m * ldc + n] = v + bias[n];
  } else if (EPI == EPI_GATE) {
    float g = 1.f / (1.f + expf(-(v + bias[n])));
    int half = N >> 1;
    if (n < half) Zout[(size_t)m * half + n] = g;
    else RHout[(size_t)m * half + (n - half)] = g * Hb[(size_t)m * ldh + (n - half)];
  } else if (EPI == EPI_NEWH) {
    float nv = tanhf(v + bias[n]);
    float z = Zin[(size_t)m * N + n];
    float h = Hb[(size_t)m * ldh + n];
    C[(size_t)m * ldc + n] = (1.f - z) * h + z * nv;
  }
}

// row softmax over NOC=151 columns, one block per row
__global__ __launch_bounds__(256) void softmax_k(const float* __restrict__ X,
                                                 float* __restrict__ P)
{
  int row = blockIdx.x;
  int t = threadIdx.x;
  __shared__ float red[4];
  float x = (t < NOC) ? X[row * NOC + t] : -3.4e38f;
  float m = x;
#pragma unroll
  for (int o = 32; o > 0; o >>= 1) m = fmaxf(m, __shfl_xor(m, o, 64));
  if ((t & 63) == 0) red[t >> 6] = m;
  __syncthreads();
  float mm = fmaxf(fmaxf(red[0], red[1]), fmaxf(red[2], red[3]));
  float e = (t < NOC) ? expf(x - mm) : 0.f;
  float s = e;
#pragma unroll
  for (int o = 32; o > 0; o >>= 1) s += __shfl_xor(s, o, 64);
  __syncthreads();
  if ((t & 63) == 0) red[t >> 6] = s;
  __syncthreads();
  float ss = red[0] + red[1] + red[2] + red[3];
  if (t < NOC) P[row * NOC + t] = e / ss;
}

// deterministic scatter-free m_obj
__global__ __launch_bounds__(256) void m_obj_gather_k(const float* __restrict__ hm,
                                                      const int* __restrict__ ridx,
                                                      float* __restrict__ m_obj)
{
  int n = blockIdx.x;
  int im = n >> 6;
  int col = threadIdx.x;
  float acc0 = 0.f, acc1 = 0.f;
  int r0 = im * RPI, r1 = r0 + RPI;
  for (int r = r0; r < r1; ++r) {
    int s = ridx[r * 3 + 1];
    int o = ridx[r * 3 + 2];
    int cnt = (s == n) + (o == n);
    if (cnt) {
      float f = (float)cnt;
      acc0 = fmaf(f, hm[r * H + col], acc0);
      acc1 = fmaf(f, hm[r * H + col + 256], acc1);
    }
  }
  m_obj[n * H + col] = acc0;
  m_obj[n * H + col + 256] = acc1;
}

// per-class NMS (stable descending bitonic sort + greedy suppression)
__global__ __launch_bounds__(512) void nms_k(const float* __restrict__ probs2,
                                             const float* __restrict__ boxes,
                                             float* __restrict__ keepmask)
{
  int c = blockIdx.x + 1;
  int t = threadIdx.x;
  __shared__ float sc[512];
  __shared__ int   si[512];
  __shared__ float bx0[512], by0[512], bx1[512], by1[512], sar[512];
  __shared__ int   skeep[512];

  sc[t] = probs2[t * NOC + c];
  si[t] = t;
  __syncthreads();

  for (int k = 2; k <= 512; k <<= 1) {
    for (int j = k >> 1; j > 0; j >>= 1) {
      int p = t ^ j;
      if (p > t) {
        float s1 = sc[t], s2 = sc[p];
        int   i1 = si[t], i2 = si[p];
        bool tBefore = (s1 > s2) || (s1 == s2 && i1 < i2);
        bool up = ((t & k) == 0);
        if (up != tBefore) { sc[t] = s2; sc[p] = s1; si[t] = i2; si[p] = i1; }
      }
      __syncthreads();
    }
  }

  {
    const float* b = &boxes[(si[t] * NOC + c) * 4];
    float x0 = b[0], y0 = b[1], x1 = b[2], y1 = b[3];
    bx0[t] = x0; by0[t] = y0; bx1[t] = x1; by1[t] = y1;
    sar[t] = (x1 - x0) * (y1 - y0);
    skeep[t] = 1;
  }
  __syncthreads();

  for (int i = 0; i < 511; ++i) {
    if (skeep[i] && t > i && skeep[t]) {
      float lx = fmaxf(bx0[i], bx0[t]);
      float ly = fmaxf(by0[i], by0[t]);
      float rx = fminf(bx1[i], bx1[t]);
      float ry = fminf(by1[i], by1[t]);
      float w = fmaxf(rx - lx, 0.f);
      float h = fmaxf(ry - ly, 0.f);
      float inter = w * h;
      float iou = inter / (sar[i] + sar[t] - inter + 1e-9f);
      if (iou > IOU_THRESH) skeep[t] = 0;
    }
    __syncthreads();
  }

  keepmask[(c - 1) * N_OBJ + si[t]] = skeep[t] ? 1.f : 0.f;
}

__global__ void pred_k(const float* __restrict__ probs2,
                       const float* __restrict__ keepmask,
                       float* __restrict__ out)
{
  int i = threadIdx.x + blockIdx.x * 256;
  if (i >= N_OBJ) return;
  float best = -1.f;
  int bc = 0;
  for (int c = 0; c < NOC - 1; ++c) {
    float v = keepmask[c * N_OBJ + i] * probs2[i * NOC + c + 1];
    if (v > best) { best = v; bc = c; }
  }
  out[i] = (float)(bc + 1);
}

extern "C" void kernel_launch(void* const* d_in, const int* in_sizes, int n_in,
                              void* d_out, int out_size, void* d_ws, size_t ws_size,
                              hipStream_t stream) {
  const float* obj_fmaps  = (const float*)d_in[1];
  const float* obj_logits = (const float*)d_in[2];
  const int*   rel_inds   = (const int*)d_in[3];
  const float* vr         = (const float*)d_in[4];
  const float* boxes      = (const float*)d_in[5];
  const float* W_obj_proj = (const float*)d_in[6];
  const float* b_obj_proj = (const float*)d_in[7];
  const float* W_rel_proj = (const float*)d_in[8];
  const float* b_rel_proj = (const float*)d_in[9];
  const float* W_emb      = (const float*)d_in[10];
  const float* W_msg_rel  = (const float*)d_in[11];
  const float* W_msg_obj  = (const float*)d_in[12];
  const float* W_gru_obj  = (const float*)d_in[13];
  const float* U_gru_obj  = (const float*)d_in[14];
  const float* b_gru_obj  = (const float*)d_in[15];
  const float* W_gru_rel  = (const float*)d_in[16];
  const float* U_gru_rel  = (const float*)d_in[17];
  const float* b_gru_rel  = (const float*)d_in[18];
  const float* W_cls_rel  = (const float*)d_in[19];
  const float* b_cls_rel  = (const float*)d_in[20];
  const float* W_cls_obj  = (const float*)d_in[21];
  const float* b_cls_obj  = (const float*)d_in[22];

  float* ws = (float*)d_ws;
  const size_t RH = (size_t)R_REL * H;
  const size_t NH = (size_t)N_OBJ * H;
  float* h_rel  = ws;
  float* m_rel  = h_rel  + RH;   // also aliased as split-K partial scratch
  float* z_rel  = m_rel  + RH;   // aliased with hm
  float* rh_rel = z_rel  + RH;
  float* h_obj  = rh_rel + RH;
  float* m_obj  = h_obj  + NH;
  float* z_obj  = m_obj  + NH;
  float* rh_obj = z_obj  + NH;
  float* obj_probs  = rh_obj + NH;
  float* obj_probs2 = obj_probs  + (size_t)N_OBJ * NOC;
  float* keepmask   = obj_probs2 + (size_t)N_OBJ * NOC;
  float* hm   = z_rel;
  float* part = m_rel;           // 4.19M floats of dead scratch at each use site
  float* fend = keepmask + (size_t)(NOC - 1) * N_OBJ;

  u16* bt = (u16*)fend;
  const int KP_HOBJ = 4256;
  const int KP_HREL = 4096;
  const int KP_MSG  = 512;
  const int KP_GRU  = 1024;
  const int KP_CLS  = 512;
  u16* p = bt;
  u16* bt_hobj_h = p; p += (size_t)H * KP_HOBJ;      u16* bt_hobj_l = p; p += (size_t)H * KP_HOBJ;
  u16* bt_hrel_h = p; p += (size_t)H * KP_HREL;      u16* bt_hrel_l = p; p += (size_t)H * KP_HREL;
  u16* bt_mrel_h = p; p += (size_t)H * KP_MSG;       u16* bt_mrel_l = p; p += (size_t)H * KP_MSG;
  u16* bt_hm_h   = p; p += (size_t)H * KP_MSG;       u16* bt_hm_l   = p; p += (size_t)H * KP_MSG;
  u16* bt_gr_h   = p; p += (size_t)2 * H * KP_GRU;   u16* bt_gr_l   = p; p += (size_t)2 * H * KP_GRU;
  u16* bt_nr_h   = p; p += (size_t)H * KP_GRU;       u16* bt_nr_l   = p; p += (size_t)H * KP_GRU;
  u16* bt_go_h   = p; p += (size_t)2 * H * KP_GRU;   u16* bt_go_l   = p; p += (size_t)2 * H * KP_GRU;
  u16* bt_no_h   = p; p += (size_t)H * KP_GRU;       u16* bt_no_l   = p; p += (size_t)H * KP_GRU;
  u16* bt_cr_h   = p; p += (size_t)128 * KP_CLS;     u16* bt_cr_l   = p; p += (size_t)128 * KP_CLS;
  u16* bt_co_h   = p; p += (size_t)256 * KP_CLS;     u16* bt_co_l   = p; p += (size_t)256 * KP_CLS;

  float* out_logits = (float*)d_out;
  float* out_preds  = out_logits + (size_t)N_OBJ * NOC;
  float* out_rel    = out_preds + N_OBJ;

  dim3 blk(256);
  dim3 blk5(512);
#define PREP(W1, ld1, K1, W2, ld2, K2, coff, NC, NN, KP, oh, ol) \
  prep_bt<<<dim3(((KP) + 63) / 64, ((NN) + 63) / 64), 256, 0, stream>>>( \
      W1, ld1, K1, W2, ld2, K2, coff, NC, NN, KP, oh, ol)

  PREP(W_obj_proj, H, OBJ_DIM, W_emb, H, NOC, 0, H, H, KP_HOBJ, bt_hobj_h, bt_hobj_l);
  PREP(W_rel_proj, H, OBJ_DIM, (const float*)nullptr, 0, 0, 0, H, H, KP_HREL, bt_hrel_h, bt_hrel_l);
  PREP(W_msg_rel, H, H, (const float*)nullptr, 0, 0, 0, H, H, KP_MSG, bt_mrel_h, bt_mrel_l);
  PREP(W_msg_obj, H, H, (const float*)nullptr, 0, 0, 0, H, H, KP_MSG, bt_hm_h, bt_hm_l);
  PREP(W_gru_rel, 3 * H, H, U_gru_rel, 3 * H, H, 0, 2 * H, 2 * H, KP_GRU, bt_gr_h, bt_gr_l);
  PREP(W_gru_rel, 3 * H, H, U_gru_rel, 3 * H, H, 2 * H, H, H, KP_GRU, bt_nr_h, bt_nr_l);
  PREP(W_gru_obj, 3 * H, H, U_gru_obj, 3 * H, H, 0, 2 * H, 2 * H, KP_GRU, bt_go_h, bt_go_l);
  PREP(W_gru_obj, 3 * H, H, U_gru_obj, 3 * H, H, 2 * H, H, H, KP_GRU, bt_no_h, bt_no_l);
  PREP(W_cls_rel, NRC, H, (const float*)nullptr, 0, 0, 0, NRC, 128, KP_CLS, bt_cr_h, bt_cr_l);
  PREP(W_cls_obj, NOC, H, (const float*)nullptr, 0, 0, 0, NOC, 256, KP_CLS, bt_co_h, bt_co_l);

  softmax_k<<<N_OBJ, 256, 0, stream>>>(obj_logits, obj_probs);

#define MG(EPI, DUAL, GATH, PAIR, SPLIT, grid, M, N, K1, K2, nkt, A1, lda1, A2, lda2, \
           Bh, Bl, Bh2, Bl2, bias, C, ldc, C2, ridx, Hb, ldh, Zin, Zo, RHo, part, ktc) \
  mgemm_k<EPI, DUAL, GATH, PAIR, SPLIT><<<grid, blk5, 0, stream>>>( \
      M, N, K1, K2, nkt, A1, lda1, A2, lda2, Bh, Bl, Bh2, Bl2, bias, C, ldc, C2, \
      ridx, Hb, ldh, Zin, Zo, RHo, part, ktc)

  // h_obj = obj_fmaps @ W_obj_proj + obj_probs @ W_emb + b  (split-K S=16)
  MG(EPI_STORE, true, false, false, true, dim3(4, 4, 16), N_OBJ, H, OBJ_DIM, NOC, KP_HOBJ / 32,
     obj_fmaps, OBJ_DIM, obj_probs, NOC, bt_hobj_h, bt_hobj_l, nullptr, nullptr,
     nullptr, nullptr, 0, nullptr, nullptr, nullptr, 0, nullptr, nullptr, nullptr, part, 9);
  epi_reduce<EPI_BIAS><<<(N_OBJ * H + 255) / 256, blk, 0, stream>>>(
      16, N_OBJ, H, H, part, b_obj_proj, h_obj, H, nullptr, 0, nullptr, nullptr, nullptr);

  // h_rel = vr @ W_rel_proj + b_rel_proj  (256 blocks x 8 waves)
  MG(EPI_BIAS, false, false, false, false, dim3(4, 64), R_REL, H, OBJ_DIM, 0, KP_HREL / 32,
     vr, OBJ_DIM, nullptr, 0, bt_hrel_h, bt_hrel_l, nullptr, nullptr,
     b_rel_proj, h_rel, H, nullptr, nullptr, nullptr, 0, nullptr, nullptr, nullptr, nullptr, 0);

  for (int it = 0; it < T_ITERS; ++it) {
    // paired: z=0: m_rel = (h_obj[s]+h_obj[o]) @ W_msg_rel ; z=1: hm = h_rel @ W_msg_obj
    MG(EPI_STORE, false, true, true, false, dim3(4, 64, 2), R_REL, H, H, 0, KP_MSG / 32,
       h_obj, H, h_rel, H, bt_mrel_h, bt_mrel_l, bt_hm_h, bt_hm_l,
       nullptr, m_rel, H, hm, rel_inds, nullptr, 0, nullptr, nullptr, nullptr, nullptr, 0);
    m_obj_gather_k<<<N_OBJ, 256, 0, stream>>>(hm, rel_inds, m_obj);

    // GRU rel gates
    MG(EPI_GATE, true, false, false, false, dim3(8, 64), R_REL, 2 * H, H, H, KP_GRU / 32,
       m_rel, H, h_rel, H, bt_gr_h, bt_gr_l, nullptr, nullptr,
       b_gru_rel, nullptr, 0, nullptr, nullptr, h_rel, H, nullptr, z_rel, rh_rel, nullptr, 0);
    // GRU rel candidate + h update
    MG(EPI_NEWH, true, false, false, false, dim3(4, 64), R_REL, H, H, H, KP_GRU / 32,
       m_rel, H, rh_rel, H, bt_nr_h, bt_nr_l, nullptr, nullptr,
       b_gru_rel + 2 * H, h_rel, H, nullptr, nullptr, h_rel, H, z_rel, nullptr, nullptr, nullptr, 0);

    // GRU obj gates (split-K S=8, Npad=1024)
    MG(EPI_STORE, true, false, false, true, dim3(8, 4, 8), N_OBJ, 2 * H, H, H, KP_GRU / 32,
       m_obj, H, h_obj, H, bt_go_h, bt_go_l, nullptr, nullptr,
       nullptr, nullptr, 0, nullptr, nullptr, nullptr, 0, nullptr, nullptr, nullptr, part, 4);
    epi_reduce<EPI_GATE><<<(N_OBJ * 2 * H + 255) / 256, blk, 0, stream>>>(
        8, N_OBJ, 2 * H, 2 * H, part, b_gru_obj, nullptr, 0, h_obj, H, nullptr, z_obj, rh_obj);
    // GRU obj candidate + h update (split-K S=16)
    MG(EPI_STORE, true, false, false, true, dim3(4, 4, 16), N_OBJ, H, H, H, KP_GRU / 32,
       m_obj, H, rh_obj, H, bt_no_h, bt_no_l, nullptr, nullptr,
       nullptr, nullptr, 0, nullptr, nullptr, nullptr, 0, nullptr, nullptr, nullptr, part, 2);
    epi_reduce<EPI_NEWH><<<(N_OBJ * H + 255) / 256, blk, 0, stream>>>(
        16, N_OBJ, H, H, part, b_gru_obj + 2 * H, h_obj, H, h_obj, H, z_obj, nullptr, nullptr);
  }

  // rel_logits = h_rel @ W_cls_rel + b (N=51, padded bt to 128, split-K S=4)
  MG(EPI_STORE, false, false, false, true, dim3(1, 64, 4), R_REL, NRC, H, 0, KP_CLS / 32,
     h_rel, H, nullptr, 0, bt_cr_h, bt_cr_l, nullptr, nullptr,
     nullptr, nullptr, 0, nullptr, nullptr, nullptr, 0, nullptr, nullptr, nullptr, part, 4);
  epi_reduce<EPI_BIAS><<<(R_REL * 128 + 255) / 256, blk, 0, stream>>>(
      4, R_REL, NRC, 128, part, b_cls_rel, out_rel, NRC, nullptr, 0, nullptr, nullptr, nullptr);
  // obj_logits_out = h_obj @ W_cls_obj + b (N=151, padded bt to 256, split-K S=16)
  MG(EPI_STORE, false, false, false, true, dim3(2, 4, 16), N_OBJ, NOC, H, 0, KP_CLS / 32,
     h_obj, H, nullptr, 0, bt_co_h, bt_co_l, nullptr, nullptr,
     nullptr, nullptr, 0, nullptr, nullptr, nullptr, 0, nullptr, nullptr, nullptr, part, 1);
  epi_reduce<EPI_BIAS><<<(N_OBJ * 256 + 255) / 256, blk, 0, stream>>>(
      16, N_OBJ, NOC, 256, part, b_cls_obj, out_logits, NOC, nullptr, 0, nullptr, nullptr, nullptr);

  // softmax -> NMS -> preds
  softmax_k<<<N_OBJ, 256, 0, stream>>>(out_logits, obj_probs2);
  nms_k<<<NOC - 1, 512, 0, stream>>>(obj_probs2, boxes, keepmask);
  pred_k<<<2, 256, 0, stream>>>(obj_probs2, keepmask, out_preds);
}